// Round 1
// baseline (824.636 us; speedup 1.0000x reference)
//
#include <hip/hip_runtime.h>
#include <math.h>

#define N_NODES 50000
#define N_EDGES 800000
#define ETOT    (N_EDGES + N_NODES)   // 850000 edges incl. self-loops
#define DIM_IN  128
#define HID     64
#define NHEAD   4
#define HDIM    256                   // NHEAD*HID
#define NEG_SLOPE 0.2f

static __device__ __forceinline__ float gelu_exact(float x) {
    return 0.5f * x * (1.0f + erff(x * 0.70710678118654752f));
}

// ---------------- CSR build (by dst) ----------------
__global__ void count_kernel(const int* __restrict__ ei, int* __restrict__ counts) {
    int i = blockIdx.x * 256 + threadIdx.x;
    if (i >= ETOT) return;
    int d = (i < N_EDGES) ? ei[N_EDGES + i] : (i - N_EDGES);
    atomicAdd(&counts[d], 1);
}

__global__ void scan1_kernel(const int* __restrict__ counts, int* __restrict__ offs,
                             int* __restrict__ blockSums) {
    __shared__ int s[256];
    int t = threadIdx.x, idx = blockIdx.x * 256 + t;
    int v = (idx < N_NODES) ? counts[idx] : 0;
    s[t] = v; __syncthreads();
    #pragma unroll
    for (int o = 1; o < 256; o <<= 1) {
        int add = (t >= o) ? s[t - o] : 0;
        __syncthreads();
        s[t] += add;
        __syncthreads();
    }
    if (idx < N_NODES) offs[idx] = s[t] - v;   // exclusive within block
    if (t == 255) blockSums[blockIdx.x] = s[t];
}

__global__ void scan2_kernel(const int* __restrict__ blockSums, int* __restrict__ blockScan, int nb) {
    __shared__ int s[256];
    int t = threadIdx.x;
    int v = (t < nb) ? blockSums[t] : 0;
    s[t] = v; __syncthreads();
    #pragma unroll
    for (int o = 1; o < 256; o <<= 1) {
        int add = (t >= o) ? s[t - o] : 0;
        __syncthreads();
        s[t] += add;
        __syncthreads();
    }
    blockScan[t] = s[t] - v;  // exclusive
}

__global__ void scan3_kernel(int* __restrict__ offs, const int* __restrict__ blockScan) {
    int idx = blockIdx.x * 256 + threadIdx.x;
    if (idx < N_NODES) offs[idx] += blockScan[blockIdx.x];
    if (idx == 0) offs[N_NODES] = ETOT;
}

__global__ void fill_kernel(const int* __restrict__ ei, const int* __restrict__ offs,
                            int* __restrict__ cursor, int* __restrict__ csrc) {
    int i = blockIdx.x * 256 + threadIdx.x;
    if (i >= ETOT) return;
    int s, d;
    if (i < N_EDGES) { s = ei[i]; d = ei[N_EDGES + i]; } else { s = d = i - N_EDGES; }
    int pos = offs[d] + atomicAdd(&cursor[d], 1);
    csrc[pos] = s;
}

// ---------------- GEMM: C[M,256] = A[M,K] @ B[K,256], K % 16 == 0 ----------------
__global__ __launch_bounds__(256) void gemm_kernel(
    const float* __restrict__ A, const float* __restrict__ B, float* __restrict__ C,
    int M, int K)
{
    __shared__ float As[16][68];   // [k][m], padded for 16B-aligned float4 reads
    __shared__ float Bs[16][64];
    const int tid = threadIdx.x;
    const int bm = blockIdx.x, bn = blockIdx.y;
    const int tr = tid >> 4, tc = tid & 15;
    const int ar = tid >> 2;            // 0..63  (A-load row within tile)
    const int ak = (tid & 3) << 2;      // 0,4,8,12
    const int bk = tid >> 4;            // 0..15  (B-load k within tile)
    const int bc = (tid & 15) << 2;
    const int arow = bm * 64 + ar;

    float4 acc0 = {0,0,0,0}, acc1 = {0,0,0,0}, acc2 = {0,0,0,0}, acc3 = {0,0,0,0};

    for (int k0 = 0; k0 < K; k0 += 16) {
        float4 av = make_float4(0.f, 0.f, 0.f, 0.f);
        if (arow < M) av = *(const float4*)(A + (size_t)arow * K + k0 + ak);
        As[ak + 0][ar] = av.x; As[ak + 1][ar] = av.y;
        As[ak + 2][ar] = av.z; As[ak + 3][ar] = av.w;
        *(float4*)(&Bs[bk][bc]) = *(const float4*)(B + (size_t)(k0 + bk) * HDIM + bn * 64 + bc);
        __syncthreads();
        #pragma unroll
        for (int kk = 0; kk < 16; ++kk) {
            float4 a = *(const float4*)(&As[kk][tr << 2]);
            float4 b = *(const float4*)(&Bs[kk][tc << 2]);
            acc0.x += a.x*b.x; acc0.y += a.x*b.y; acc0.z += a.x*b.z; acc0.w += a.x*b.w;
            acc1.x += a.y*b.x; acc1.y += a.y*b.y; acc1.z += a.y*b.z; acc1.w += a.y*b.w;
            acc2.x += a.z*b.x; acc2.y += a.z*b.y; acc2.z += a.z*b.z; acc2.w += a.z*b.w;
            acc3.x += a.w*b.x; acc3.y += a.w*b.y; acc3.z += a.w*b.z; acc3.w += a.w*b.w;
        }
        __syncthreads();
    }
    const int row0 = bm * 64 + (tr << 2);
    const int col0 = bn * 64 + (tc << 2);
    if (row0 + 0 < M) *(float4*)(C + (size_t)(row0 + 0) * HDIM + col0) = acc0;
    if (row0 + 1 < M) *(float4*)(C + (size_t)(row0 + 1) * HDIM + col0) = acc1;
    if (row0 + 2 < M) *(float4*)(C + (size_t)(row0 + 2) * HDIM + col0) = acc2;
    if (row0 + 3 < M) *(float4*)(C + (size_t)(row0 + 3) * HDIM + col0) = acc3;
}

// ---------------- per-node attention coefficients ----------------
__global__ __launch_bounds__(256) void esed_kernel(
    const float* __restrict__ h, const float* __restrict__ a_s, const float* __restrict__ a_d,
    float* __restrict__ es, float* __restrict__ ed)
{
    int w = (blockIdx.x * 256 + threadIdx.x) >> 6;
    int lane = threadIdx.x & 63;
    if (w >= N_NODES) return;
    const float* hp = h + (size_t)w * HDIM;
    #pragma unroll
    for (int hd = 0; hd < NHEAD; ++hd) {
        float hv = hp[hd * 64 + lane];
        float ps = hv * a_s[hd * 64 + lane];
        float pd = hv * a_d[hd * 64 + lane];
        #pragma unroll
        for (int o = 32; o; o >>= 1) {
            ps += __shfl_xor(ps, o, 64);
            pd += __shfl_xor(pd, o, 64);
        }
        if (lane == 0) { es[w * 4 + hd] = ps; ed[w * 4 + hd] = pd; }
    }
}

// ---------------- one wave per dst node: online softmax + weighted gather ----------------
__global__ __launch_bounds__(256) void aggregate_kernel(
    const float* __restrict__ h, const float4* __restrict__ es4, const float4* __restrict__ ed4,
    const int* __restrict__ offs, const int* __restrict__ csrc,
    const float* __restrict__ bias, float* __restrict__ xout)
{
    int w = (blockIdx.x * 256 + threadIdx.x) >> 6;
    int lane = threadIdx.x & 63;
    if (w >= N_NODES) return;
    int hd = lane >> 4;      // this lane's head (float4 at j=lane*4 lies in head lane/16)

    float4 edv = ed4[w];
    float ed_s = (hd == 0) ? edv.x : (hd == 1) ? edv.y : (hd == 2) ? edv.z : edv.w;

    float m = -INFINITY, z = 0.f;
    float4 acc = {0.f, 0.f, 0.f, 0.f};

    int beg = offs[w], end = offs[w + 1];
    for (int i = beg; i < end; ++i) {
        int s = csrc[i];
        float4 esv = es4[s];
        float e = ((hd == 0) ? esv.x : (hd == 1) ? esv.y : (hd == 2) ? esv.z : esv.w) + ed_s;
        e = (e > 0.f) ? e : NEG_SLOPE * e;
        float4 hv = *(const float4*)(h + (size_t)s * HDIM + (lane << 2));
        float nm = fmaxf(m, e);
        float sc = __expf(m - nm);    // first iter: exp(-inf)=0
        float wg = __expf(e - nm);
        m = nm;
        z = z * sc + wg;
        acc.x = acc.x * sc + wg * hv.x;
        acc.y = acc.y * sc + wg * hv.y;
        acc.z = acc.z * sc + wg * hv.z;
        acc.w = acc.w * sc + wg * hv.w;
    }
    float inv = 1.f / z;
    acc.x *= inv; acc.y *= inv; acc.z *= inv; acc.w *= inv;
    // head mean: sum lanes {l, l^16, l^32, l^48}
    acc.x += __shfl_xor(acc.x, 16, 64); acc.x += __shfl_xor(acc.x, 32, 64);
    acc.y += __shfl_xor(acc.y, 16, 64); acc.y += __shfl_xor(acc.y, 32, 64);
    acc.z += __shfl_xor(acc.z, 16, 64); acc.z += __shfl_xor(acc.z, 32, 64);
    acc.w += __shfl_xor(acc.w, 16, 64); acc.w += __shfl_xor(acc.w, 32, 64);
    if (lane < 16) {
        float4 bv = *(const float4*)(bias + (lane << 2));
        float4 r;
        r.x = gelu_exact(0.25f * acc.x + bv.x);
        r.y = gelu_exact(0.25f * acc.y + bv.y);
        r.z = gelu_exact(0.25f * acc.z + bv.z);
        r.w = gelu_exact(0.25f * acc.w + bv.w);
        *(float4*)(xout + (size_t)w * HID + (lane << 2)) = r;
    }
}

// ---------------- final linear + sigmoid ----------------
__global__ __launch_bounds__(256) void final_kernel(
    const float* __restrict__ x, const float* __restrict__ fcW, const float* __restrict__ fcb,
    float* __restrict__ out)
{
    int w = (blockIdx.x * 256 + threadIdx.x) >> 6;
    int lane = threadIdx.x & 63;
    if (w >= N_NODES) return;
    float p = x[(size_t)w * HID + lane] * fcW[lane];
    #pragma unroll
    for (int o = 32; o; o >>= 1) p += __shfl_xor(p, o, 64);
    if (lane == 0) out[w] = 1.f / (1.f + __expf(-(p + fcb[0])));
}

extern "C" void kernel_launch(void* const* d_in, const int* in_sizes, int n_in,
                              void* d_out, int out_size, void* d_ws, size_t ws_size,
                              hipStream_t stream) {
    const float* x    = (const float*)d_in[0];
    const int*   ei   = (const int*)d_in[1];
    const float* W1   = (const float*)d_in[2];
    const float* as1  = (const float*)d_in[3];
    const float* ad1  = (const float*)d_in[4];
    const float* b1   = (const float*)d_in[5];
    const float* W2   = (const float*)d_in[6];
    const float* as2  = (const float*)d_in[7];
    const float* ad2  = (const float*)d_in[8];
    const float* b2   = (const float*)d_in[9];
    const float* W3   = (const float*)d_in[10];
    const float* as3  = (const float*)d_in[11];
    const float* ad3  = (const float*)d_in[12];
    const float* b3   = (const float*)d_in[13];
    const float* fcW  = (const float*)d_in[14];
    const float* fcb  = (const float*)d_in[15];
    float* out = (float*)d_out;

    // workspace carve-up (~83 MB total)
    char* ws = (char*)d_ws;
    size_t off = 0;
    auto alloc = [&](size_t bytes) -> void* {
        void* p = ws + off;
        off += (bytes + 255) & ~(size_t)255;
        return p;
    };
    float* h     = (float*)alloc((size_t)N_NODES * HDIM * 4);  // 51.2 MB
    float* esb   = (float*)alloc((size_t)N_NODES * 4 * 4);
    float* edb   = (float*)alloc((size_t)N_NODES * 4 * 4);
    float* xA    = (float*)alloc((size_t)N_NODES * HID * 4);   // 12.8 MB
    float* xB    = (float*)alloc((size_t)N_NODES * HID * 4);   // 12.8 MB
    int* offs    = (int*)alloc((size_t)(N_NODES + 1) * 4);
    int* counts  = (int*)alloc((size_t)2 * N_NODES * 4);       // counts + cursor contiguous
    int* cursor  = counts + N_NODES;
    int* bsums   = (int*)alloc(256 * 4);
    int* bscan   = (int*)alloc(256 * 4);
    int* csrc    = (int*)alloc((size_t)ETOT * 4);              // 3.4 MB

    const int NB      = (N_NODES + 255) / 256;   // 196
    const int EB      = (ETOT + 255) / 256;      // 3321
    const int WAVEB   = (N_NODES * 64) / 256;    // 12500 (exact)
    const dim3 gemmGrid(( N_NODES + 63) / 64, 4);

    // CSR build (graph is identical each call; ws is re-poisoned, so rebuild)
    hipMemsetAsync(counts, 0, (size_t)2 * N_NODES * 4, stream);
    count_kernel<<<EB, 256, 0, stream>>>(ei, counts);
    scan1_kernel<<<NB, 256, 0, stream>>>(counts, offs, bsums);
    scan2_kernel<<<1, 256, 0, stream>>>(bsums, bscan, NB);
    scan3_kernel<<<NB, 256, 0, stream>>>(offs, bscan);
    fill_kernel<<<EB, 256, 0, stream>>>(ei, offs, cursor, csrc);

    // layer 1
    gemm_kernel<<<gemmGrid, 256, 0, stream>>>(x, W1, h, N_NODES, DIM_IN);
    esed_kernel<<<WAVEB, 256, 0, stream>>>(h, as1, ad1, esb, edb);
    aggregate_kernel<<<WAVEB, 256, 0, stream>>>(h, (const float4*)esb, (const float4*)edb,
                                                offs, csrc, b1, xA);
    // layer 2
    gemm_kernel<<<gemmGrid, 256, 0, stream>>>(xA, W2, h, N_NODES, HID);
    esed_kernel<<<WAVEB, 256, 0, stream>>>(h, as2, ad2, esb, edb);
    aggregate_kernel<<<WAVEB, 256, 0, stream>>>(h, (const float4*)esb, (const float4*)edb,
                                                offs, csrc, b2, xB);
    // layer 3
    gemm_kernel<<<gemmGrid, 256, 0, stream>>>(xB, W3, h, N_NODES, HID);
    esed_kernel<<<WAVEB, 256, 0, stream>>>(h, as3, ad3, esb, edb);
    aggregate_kernel<<<WAVEB, 256, 0, stream>>>(h, (const float4*)esb, (const float4*)edb,
                                                offs, csrc, b3, xA);
    // final
    final_kernel<<<WAVEB, 256, 0, stream>>>(xA, fcW, fcb, out);
}

// Round 2
// 541.970 us; speedup vs baseline: 1.5216x; 1.5216x over previous
//
#include <hip/hip_runtime.h>
#include <math.h>

#define N_NODES 50000
#define N_EDGES 800000
#define ETOT    (N_EDGES + N_NODES)   // 850000 edges incl. self-loops
#define DIM_IN  128
#define HID     64
#define NHEAD   4
#define HDIM    256                   // NHEAD*HID
#define NEG_SLOPE 0.2f

static __device__ __forceinline__ float gelu_exact(float x) {
    return 0.5f * x * (1.0f + erff(x * 0.70710678118654752f));
}
static __device__ __forceinline__ unsigned short f2bf(float f) {
    unsigned u = __float_as_uint(f);
    u = (u + 0x7FFFu + ((u >> 16) & 1u)) >> 16;   // RNE
    return (unsigned short)u;
}
static __device__ __forceinline__ float b2f(unsigned short us) {
    return __uint_as_float(((unsigned)us) << 16);
}

// ---------------- CSR build (by dst) ----------------
__global__ void count_kernel(const int* __restrict__ ei, int* __restrict__ counts) {
    int i = blockIdx.x * 256 + threadIdx.x;
    if (i >= ETOT) return;
    int d = (i < N_EDGES) ? ei[N_EDGES + i] : (i - N_EDGES);
    atomicAdd(&counts[d], 1);
}

__global__ void scan1_kernel(const int* __restrict__ counts, int* __restrict__ offs,
                             int* __restrict__ blockSums) {
    __shared__ int s[256];
    int t = threadIdx.x, idx = blockIdx.x * 256 + t;
    int v = (idx < N_NODES) ? counts[idx] : 0;
    s[t] = v; __syncthreads();
    #pragma unroll
    for (int o = 1; o < 256; o <<= 1) {
        int add = (t >= o) ? s[t - o] : 0;
        __syncthreads();
        s[t] += add;
        __syncthreads();
    }
    if (idx < N_NODES) offs[idx] = s[t] - v;   // exclusive within block
    if (t == 255) blockSums[blockIdx.x] = s[t];
}

__global__ void scan2_kernel(const int* __restrict__ blockSums, int* __restrict__ blockScan, int nb) {
    __shared__ int s[256];
    int t = threadIdx.x;
    int v = (t < nb) ? blockSums[t] : 0;
    s[t] = v; __syncthreads();
    #pragma unroll
    for (int o = 1; o < 256; o <<= 1) {
        int add = (t >= o) ? s[t - o] : 0;
        __syncthreads();
        s[t] += add;
        __syncthreads();
    }
    blockScan[t] = s[t] - v;  // exclusive
}

__global__ void scan3_kernel(int* __restrict__ offs, const int* __restrict__ blockScan) {
    int idx = blockIdx.x * 256 + threadIdx.x;
    if (idx < N_NODES) offs[idx] += blockScan[blockIdx.x];
    if (idx == 0) offs[N_NODES] = ETOT;
}

__global__ void fill_kernel(const int* __restrict__ ei, const int* __restrict__ offs,
                            int* __restrict__ cursor, int* __restrict__ csrc) {
    int i = blockIdx.x * 256 + threadIdx.x;
    if (i >= ETOT) return;
    int s, d;
    if (i < N_EDGES) { s = ei[i]; d = ei[N_EDGES + i]; } else { s = d = i - N_EDGES; }
    int pos = offs[d] + atomicAdd(&cursor[d], 1);
    csrc[pos] = s;
}

// ---------------- GEMM + fused attention coeffs + bf16 h ----------------
// C[M,256] = A[M,K] @ B[K,256]; per-tile head = blockIdx.y; writes h (bf16),
// es[row][head], ed[row][head] computed from f32 accumulators.
__global__ __launch_bounds__(256) void gemm_kernel(
    const float* __restrict__ A, const float* __restrict__ B,
    const float* __restrict__ a_s, const float* __restrict__ a_d,
    unsigned short* __restrict__ h_bf, float* __restrict__ es, float* __restrict__ ed,
    int M, int K)
{
    __shared__ float As[16][68];   // [k][m], padded
    __shared__ float Bs[16][64];
    const int tid = threadIdx.x;
    const int bm = blockIdx.x, bn = blockIdx.y;   // bn == head
    const int tr = tid >> 4, tc = tid & 15;
    const int ar = tid >> 2;            // 0..63
    const int ak = (tid & 3) << 2;      // 0,4,8,12
    const int bk = tid >> 4;            // 0..15
    const int bc = (tid & 15) << 2;
    const int arow = bm * 64 + ar;

    float4 acc0 = {0,0,0,0}, acc1 = {0,0,0,0}, acc2 = {0,0,0,0}, acc3 = {0,0,0,0};

    for (int k0 = 0; k0 < K; k0 += 16) {
        float4 av = make_float4(0.f, 0.f, 0.f, 0.f);
        if (arow < M) av = *(const float4*)(A + (size_t)arow * K + k0 + ak);
        As[ak + 0][ar] = av.x; As[ak + 1][ar] = av.y;
        As[ak + 2][ar] = av.z; As[ak + 3][ar] = av.w;
        *(float4*)(&Bs[bk][bc]) = *(const float4*)(B + (size_t)(k0 + bk) * HDIM + bn * 64 + bc);
        __syncthreads();
        #pragma unroll
        for (int kk = 0; kk < 16; ++kk) {
            float4 a = *(const float4*)(&As[kk][tr << 2]);
            float4 b = *(const float4*)(&Bs[kk][tc << 2]);
            acc0.x += a.x*b.x; acc0.y += a.x*b.y; acc0.z += a.x*b.z; acc0.w += a.x*b.w;
            acc1.x += a.y*b.x; acc1.y += a.y*b.y; acc1.z += a.y*b.z; acc1.w += a.y*b.w;
            acc2.x += a.z*b.x; acc2.y += a.z*b.y; acc2.z += a.z*b.z; acc2.w += a.z*b.w;
            acc3.x += a.w*b.x; acc3.y += a.w*b.y; acc3.z += a.w*b.z; acc3.w += a.w*b.w;
        }
        __syncthreads();
    }
    const int row0 = bm * 64 + (tr << 2);
    const int col0 = bn * 64 + (tc << 2);
    const float4 asv = *(const float4*)(a_s + bn * 64 + (tc << 2));
    const float4 adv = *(const float4*)(a_d + bn * 64 + (tc << 2));
    float4 accs[4] = {acc0, acc1, acc2, acc3};
    #pragma unroll
    for (int r = 0; r < 4; ++r) {
        float4 a = accs[r];
        float ps = a.x*asv.x + a.y*asv.y + a.z*asv.z + a.w*asv.w;
        float pd = a.x*adv.x + a.y*adv.y + a.z*adv.z + a.w*adv.w;
        #pragma unroll
        for (int o = 8; o; o >>= 1) { ps += __shfl_xor(ps, o, 16); pd += __shfl_xor(pd, o, 16); }
        int row = row0 + r;
        if (row < M) {
            if (tc == 0) { es[row * 4 + bn] = ps; ed[row * 4 + bn] = pd; }
            ushort4 hb;
            hb.x = f2bf(a.x); hb.y = f2bf(a.y); hb.z = f2bf(a.z); hb.w = f2bf(a.w);
            *(ushort4*)(h_bf + (size_t)row * HDIM + col0) = hb;
        }
    }
}

// ---------------- per-node softmax stats + edge weights ----------------
// 16 lanes per node; alpha[e][h] = exp(lrelu(es[src][h]+ed[dst][h]) - m) / z
__global__ __launch_bounds__(256) void mz_alpha_kernel(
    const float4* __restrict__ es4, const float4* __restrict__ ed4,
    const int* __restrict__ offs, const int* __restrict__ csrc,
    float4* __restrict__ alpha4)
{
    int w = (blockIdx.x * 256 + threadIdx.x) >> 4;
    if (w >= N_NODES) return;
    int sl = threadIdx.x & 15;
    int beg = offs[w], end = offs[w + 1];
    float4 edv = ed4[w];

    float4 mx = {-INFINITY, -INFINITY, -INFINITY, -INFINITY};
    for (int i = beg + sl; i < end; i += 16) {
        float4 e = es4[csrc[i]];
        e.x += edv.x; e.y += edv.y; e.z += edv.z; e.w += edv.w;
        e.x = (e.x > 0.f) ? e.x : NEG_SLOPE * e.x;
        e.y = (e.y > 0.f) ? e.y : NEG_SLOPE * e.y;
        e.z = (e.z > 0.f) ? e.z : NEG_SLOPE * e.z;
        e.w = (e.w > 0.f) ? e.w : NEG_SLOPE * e.w;
        mx.x = fmaxf(mx.x, e.x); mx.y = fmaxf(mx.y, e.y);
        mx.z = fmaxf(mx.z, e.z); mx.w = fmaxf(mx.w, e.w);
    }
    #pragma unroll
    for (int o = 8; o; o >>= 1) {
        mx.x = fmaxf(mx.x, __shfl_xor(mx.x, o, 16));
        mx.y = fmaxf(mx.y, __shfl_xor(mx.y, o, 16));
        mx.z = fmaxf(mx.z, __shfl_xor(mx.z, o, 16));
        mx.w = fmaxf(mx.w, __shfl_xor(mx.w, o, 16));
    }
    float4 z = {0,0,0,0};
    for (int i = beg + sl; i < end; i += 16) {
        float4 e = es4[csrc[i]];
        e.x += edv.x; e.y += edv.y; e.z += edv.z; e.w += edv.w;
        e.x = (e.x > 0.f) ? e.x : NEG_SLOPE * e.x;
        e.y = (e.y > 0.f) ? e.y : NEG_SLOPE * e.y;
        e.z = (e.z > 0.f) ? e.z : NEG_SLOPE * e.z;
        e.w = (e.w > 0.f) ? e.w : NEG_SLOPE * e.w;
        z.x += __expf(e.x - mx.x); z.y += __expf(e.y - mx.y);
        z.z += __expf(e.z - mx.z); z.w += __expf(e.w - mx.w);
    }
    #pragma unroll
    for (int o = 8; o; o >>= 1) {
        z.x += __shfl_xor(z.x, o, 16);
        z.y += __shfl_xor(z.y, o, 16);
        z.z += __shfl_xor(z.z, o, 16);
        z.w += __shfl_xor(z.w, o, 16);
    }
    float4 zi = {1.f / z.x, 1.f / z.y, 1.f / z.z, 1.f / z.w};
    for (int i = beg + sl; i < end; i += 16) {
        float4 e = es4[csrc[i]];
        e.x += edv.x; e.y += edv.y; e.z += edv.z; e.w += edv.w;
        e.x = (e.x > 0.f) ? e.x : NEG_SLOPE * e.x;
        e.y = (e.y > 0.f) ? e.y : NEG_SLOPE * e.y;
        e.z = (e.z > 0.f) ? e.z : NEG_SLOPE * e.z;
        e.w = (e.w > 0.f) ? e.w : NEG_SLOPE * e.w;
        float4 al;
        al.x = __expf(e.x - mx.x) * zi.x;
        al.y = __expf(e.y - mx.y) * zi.y;
        al.z = __expf(e.z - mx.z) * zi.z;
        al.w = __expf(e.w - mx.w) * zi.w;
        alpha4[i] = al;
    }
}

// ---------------- weighted gather: one wave per dst node ----------------
__global__ __launch_bounds__(256) void gather_kernel(
    const unsigned short* __restrict__ h_bf, const float* __restrict__ alpha,
    const int* __restrict__ offs, const int* __restrict__ csrc,
    const float* __restrict__ bias, float* __restrict__ xout)
{
    int w = (blockIdx.x * 256 + threadIdx.x) >> 6;
    int lane = threadIdx.x & 63;
    if (w >= N_NODES) return;
    const int hd = lane >> 4;
    const int ch = lane << 2;

    float4 acc = {0.f, 0.f, 0.f, 0.f};
    int beg = offs[w], end = offs[w + 1];
    int i = beg;
    for (; i + 3 < end; i += 4) {
        int s0 = csrc[i], s1 = csrc[i + 1], s2 = csrc[i + 2], s3 = csrc[i + 3];
        float a0 = alpha[(size_t)(i + 0) * 4 + hd];
        float a1 = alpha[(size_t)(i + 1) * 4 + hd];
        float a2 = alpha[(size_t)(i + 2) * 4 + hd];
        float a3 = alpha[(size_t)(i + 3) * 4 + hd];
        ushort4 u0 = *(const ushort4*)(h_bf + (size_t)s0 * HDIM + ch);
        ushort4 u1 = *(const ushort4*)(h_bf + (size_t)s1 * HDIM + ch);
        ushort4 u2 = *(const ushort4*)(h_bf + (size_t)s2 * HDIM + ch);
        ushort4 u3 = *(const ushort4*)(h_bf + (size_t)s3 * HDIM + ch);
        acc.x += a0*b2f(u0.x) + a1*b2f(u1.x) + a2*b2f(u2.x) + a3*b2f(u3.x);
        acc.y += a0*b2f(u0.y) + a1*b2f(u1.y) + a2*b2f(u2.y) + a3*b2f(u3.y);
        acc.z += a0*b2f(u0.z) + a1*b2f(u1.z) + a2*b2f(u2.z) + a3*b2f(u3.z);
        acc.w += a0*b2f(u0.w) + a1*b2f(u1.w) + a2*b2f(u2.w) + a3*b2f(u3.w);
    }
    for (; i < end; ++i) {
        int s = csrc[i];
        float a = alpha[(size_t)i * 4 + hd];
        ushort4 u = *(const ushort4*)(h_bf + (size_t)s * HDIM + ch);
        acc.x += a * b2f(u.x); acc.y += a * b2f(u.y);
        acc.z += a * b2f(u.z); acc.w += a * b2f(u.w);
    }
    // head mean: sum lanes {l, l^16, l^32, l^48}
    acc.x += __shfl_xor(acc.x, 16, 64); acc.x += __shfl_xor(acc.x, 32, 64);
    acc.y += __shfl_xor(acc.y, 16, 64); acc.y += __shfl_xor(acc.y, 32, 64);
    acc.z += __shfl_xor(acc.z, 16, 64); acc.z += __shfl_xor(acc.z, 32, 64);
    acc.w += __shfl_xor(acc.w, 16, 64); acc.w += __shfl_xor(acc.w, 32, 64);
    if (lane < 16) {
        float4 bv = *(const float4*)(bias + (lane << 2));
        float4 r;
        r.x = gelu_exact(0.25f * acc.x + bv.x);
        r.y = gelu_exact(0.25f * acc.y + bv.y);
        r.z = gelu_exact(0.25f * acc.z + bv.z);
        r.w = gelu_exact(0.25f * acc.w + bv.w);
        *(float4*)(xout + (size_t)w * HID + (lane << 2)) = r;
    }
}

// ---------------- final linear + sigmoid ----------------
__global__ __launch_bounds__(256) void final_kernel(
    const float* __restrict__ x, const float* __restrict__ fcW, const float* __restrict__ fcb,
    float* __restrict__ out)
{
    int w = (blockIdx.x * 256 + threadIdx.x) >> 6;
    int lane = threadIdx.x & 63;
    if (w >= N_NODES) return;
    float p = x[(size_t)w * HID + lane] * fcW[lane];
    #pragma unroll
    for (int o = 32; o; o >>= 1) p += __shfl_xor(p, o, 64);
    if (lane == 0) out[w] = 1.f / (1.f + __expf(-(p + fcb[0])));
}

extern "C" void kernel_launch(void* const* d_in, const int* in_sizes, int n_in,
                              void* d_out, int out_size, void* d_ws, size_t ws_size,
                              hipStream_t stream) {
    const float* x    = (const float*)d_in[0];
    const int*   ei   = (const int*)d_in[1];
    const float* W1   = (const float*)d_in[2];
    const float* as1  = (const float*)d_in[3];
    const float* ad1  = (const float*)d_in[4];
    const float* b1   = (const float*)d_in[5];
    const float* W2   = (const float*)d_in[6];
    const float* as2  = (const float*)d_in[7];
    const float* ad2  = (const float*)d_in[8];
    const float* b2   = (const float*)d_in[9];
    const float* W3   = (const float*)d_in[10];
    const float* as3  = (const float*)d_in[11];
    const float* ad3  = (const float*)d_in[12];
    const float* b3   = (const float*)d_in[13];
    const float* fcW  = (const float*)d_in[14];
    const float* fcb  = (const float*)d_in[15];
    float* out = (float*)d_out;

    char* ws = (char*)d_ws;
    size_t off = 0;
    auto alloc = [&](size_t bytes) -> void* {
        void* p = ws + off;
        off += (bytes + 255) & ~(size_t)255;
        return p;
    };
    unsigned short* h_bf = (unsigned short*)alloc((size_t)N_NODES * HDIM * 2);  // 25.6 MB
    float* esb   = (float*)alloc((size_t)N_NODES * 4 * 4);
    float* edb   = (float*)alloc((size_t)N_NODES * 4 * 4);
    float* alpha = (float*)alloc((size_t)ETOT * 4 * 4);                          // 13.6 MB
    float* xA    = (float*)alloc((size_t)N_NODES * HID * 4);                     // 12.8 MB
    float* xB    = (float*)alloc((size_t)N_NODES * HID * 4);                     // 12.8 MB
    int* offs    = (int*)alloc((size_t)(N_NODES + 1) * 4);
    int* counts  = (int*)alloc((size_t)2 * N_NODES * 4);
    int* cursor  = counts + N_NODES;
    int* bsums   = (int*)alloc(256 * 4);
    int* bscan   = (int*)alloc(256 * 4);
    int* csrc    = (int*)alloc((size_t)ETOT * 4);                                // 3.4 MB

    const int NB    = (N_NODES + 255) / 256;     // 196
    const int EB    = (ETOT + 255) / 256;        // 3321
    const int WAVEB = (N_NODES * 64) / 256;      // 12500
    const int MZB   = (N_NODES + 15) / 16;       // 3125
    const dim3 gemmGrid((N_NODES + 63) / 64, 4);

    // CSR build (ws re-poisoned each call -> rebuild)
    hipMemsetAsync(counts, 0, (size_t)2 * N_NODES * 4, stream);
    count_kernel<<<EB, 256, 0, stream>>>(ei, counts);
    scan1_kernel<<<NB, 256, 0, stream>>>(counts, offs, bsums);
    scan2_kernel<<<1, 256, 0, stream>>>(bsums, bscan, NB);
    scan3_kernel<<<NB, 256, 0, stream>>>(offs, bscan);
    fill_kernel<<<EB, 256, 0, stream>>>(ei, offs, cursor, csrc);

    // layer 1
    gemm_kernel<<<gemmGrid, 256, 0, stream>>>(x, W1, as1, ad1, h_bf, esb, edb, N_NODES, DIM_IN);
    mz_alpha_kernel<<<MZB, 256, 0, stream>>>((const float4*)esb, (const float4*)edb,
                                             offs, csrc, (float4*)alpha);
    gather_kernel<<<WAVEB, 256, 0, stream>>>(h_bf, alpha, offs, csrc, b1, xA);
    // layer 2
    gemm_kernel<<<gemmGrid, 256, 0, stream>>>(xA, W2, as2, ad2, h_bf, esb, edb, N_NODES, HID);
    mz_alpha_kernel<<<MZB, 256, 0, stream>>>((const float4*)esb, (const float4*)edb,
                                             offs, csrc, (float4*)alpha);
    gather_kernel<<<WAVEB, 256, 0, stream>>>(h_bf, alpha, offs, csrc, b2, xB);
    // layer 3
    gemm_kernel<<<gemmGrid, 256, 0, stream>>>(xB, W3, as3, ad3, h_bf, esb, edb, N_NODES, HID);
    mz_alpha_kernel<<<MZB, 256, 0, stream>>>((const float4*)esb, (const float4*)edb,
                                             offs, csrc, (float4*)alpha);
    gather_kernel<<<WAVEB, 256, 0, stream>>>(h_bf, alpha, offs, csrc, b3, xA);
    // final
    final_kernel<<<WAVEB, 256, 0, stream>>>(xA, fcW, fcb, out);
}

// Round 3
// 461.380 us; speedup vs baseline: 1.7873x; 1.1747x over previous
//
#include <hip/hip_runtime.h>
#include <math.h>

#define N_NODES 50000
#define N_EDGES 800000
#define ETOT    (N_EDGES + N_NODES)   // 850000 edges incl. self-loops
#define DIM_IN  128
#define HID     64
#define NHEAD   4
#define HDIM    256                   // NHEAD*HID
#define NEG_SLOPE 0.2f

typedef __attribute__((ext_vector_type(8))) short bf16x8;
typedef __attribute__((ext_vector_type(4))) float f32x4;

static __device__ __forceinline__ float gelu_exact(float x) {
    return 0.5f * x * (1.0f + erff(x * 0.70710678118654752f));
}
static __device__ __forceinline__ unsigned short f2bf(float f) {
    unsigned u = __float_as_uint(f);
    u = (u + 0x7FFFu + ((u >> 16) & 1u)) >> 16;   // RNE
    return (unsigned short)u;
}
static __device__ __forceinline__ float b2f(unsigned short us) {
    return __uint_as_float(((unsigned)us) << 16);
}

// ---------------- CSR build (by dst) ----------------
__global__ void count_kernel(const int* __restrict__ ei, int* __restrict__ counts) {
    int i = blockIdx.x * 256 + threadIdx.x;
    if (i >= ETOT) return;
    int d = (i < N_EDGES) ? ei[N_EDGES + i] : (i - N_EDGES);
    atomicAdd(&counts[d], 1);
}

__global__ void scan1_kernel(const int* __restrict__ counts, int* __restrict__ offs,
                             int* __restrict__ blockSums) {
    __shared__ int s[256];
    int t = threadIdx.x, idx = blockIdx.x * 256 + t;
    int v = (idx < N_NODES) ? counts[idx] : 0;
    s[t] = v; __syncthreads();
    #pragma unroll
    for (int o = 1; o < 256; o <<= 1) {
        int add = (t >= o) ? s[t - o] : 0;
        __syncthreads();
        s[t] += add;
        __syncthreads();
    }
    if (idx < N_NODES) offs[idx] = s[t] - v;
    if (t == 255) blockSums[blockIdx.x] = s[t];
}

__global__ void scan2_kernel(const int* __restrict__ blockSums, int* __restrict__ blockScan, int nb) {
    __shared__ int s[256];
    int t = threadIdx.x;
    int v = (t < nb) ? blockSums[t] : 0;
    s[t] = v; __syncthreads();
    #pragma unroll
    for (int o = 1; o < 256; o <<= 1) {
        int add = (t >= o) ? s[t - o] : 0;
        __syncthreads();
        s[t] += add;
        __syncthreads();
    }
    blockScan[t] = s[t] - v;
}

__global__ void scan3_kernel(int* __restrict__ offs, const int* __restrict__ blockScan) {
    int idx = blockIdx.x * 256 + threadIdx.x;
    if (idx < N_NODES) offs[idx] += blockScan[blockIdx.x];
    if (idx == 0) offs[N_NODES] = ETOT;
}

__global__ void fill_kernel(const int* __restrict__ ei, const int* __restrict__ offs,
                            int* __restrict__ cursor, int* __restrict__ csrc) {
    int i = blockIdx.x * 256 + threadIdx.x;
    if (i >= ETOT) return;
    int s, d;
    if (i < N_EDGES) { s = ei[i]; d = ei[N_EDGES + i]; } else { s = d = i - N_EDGES; }
    int pos = offs[d] + atomicAdd(&cursor[d], 1);
    csrc[pos] = s;
}

// ---------------- dtype conversion ----------------
__global__ void convx_kernel(const float4* __restrict__ in, ushort4* __restrict__ outp, int n4) {
    int i = blockIdx.x * 256 + threadIdx.x;
    if (i >= n4) return;
    float4 v = in[i];
    ushort4 o;
    o.x = f2bf(v.x); o.y = f2bf(v.y); o.z = f2bf(v.z); o.w = f2bf(v.w);
    outp[i] = o;
}

// W[k][n] -> Wt[n][k] bf16, all three weights in one dispatch (65536 threads)
__global__ void convw_kernel(const float* __restrict__ W1, const float* __restrict__ W2,
                             const float* __restrict__ W3,
                             unsigned short* __restrict__ Wt1, unsigned short* __restrict__ Wt2,
                             unsigned short* __restrict__ Wt3) {
    int t = blockIdx.x * 256 + threadIdx.x;
    if (t < 32768) {
        int k = t >> 8, n = t & 255;
        Wt1[n * DIM_IN + k] = f2bf(W1[t]);
    } else if (t < 49152) {
        int l = t - 32768; int k = l >> 8, n = l & 255;
        Wt2[n * HID + k] = f2bf(W2[l]);
    } else if (t < 65536) {
        int l = t - 49152; int k = l >> 8, n = l & 255;
        Wt3[n * HID + k] = f2bf(W3[l]);
    }
}

// ---------------- MFMA GEMM + fused attention coeffs ----------------
// h[M,256](bf16) = A[M,K](bf16) @ W[K,256]; Wt is W transposed [256,K] bf16.
// 4 waves/block; wave = head, owns 64 output cols. es/ed from f32 accumulators.
template<int K>
__global__ __launch_bounds__(256) void gemm_mfma_kernel(
    const unsigned short* __restrict__ A, const unsigned short* __restrict__ Wt,
    const float* __restrict__ a_s, const float* __restrict__ a_d,
    unsigned short* __restrict__ h_bf, float* __restrict__ es, float* __restrict__ ed,
    int M)
{
    constexpr int KS = K / 32;
    __shared__ unsigned short hstage[64][HDIM + 8];   // +8 pad: kills 4-way write conflicts
    const int lane = threadIdx.x & 63;
    const int head = threadIdx.x >> 6;
    const int l15 = lane & 15;
    const int lg  = lane >> 4;
    const int row0 = blockIdx.x * 64;

    // preload all B fragments (Wt is tiny, L1/L2-resident)
    bf16x8 bfrag[4][KS];
    #pragma unroll
    for (int n = 0; n < 4; ++n)
        #pragma unroll
        for (int ks = 0; ks < KS; ++ks)
            bfrag[n][ks] = *(const bf16x8*)(Wt + (size_t)(head * 64 + n * 16 + l15) * K + ks * 32 + lg * 8);

    f32x4 acc[4][4];
    #pragma unroll
    for (int m = 0; m < 4; ++m)
        #pragma unroll
        for (int n = 0; n < 4; ++n)
            acc[m][n] = (f32x4){0.f, 0.f, 0.f, 0.f};

    #pragma unroll
    for (int m = 0; m < 4; ++m) {
        int row = row0 + m * 16 + l15;
        if (row >= M) row = M - 1;                 // clamp (tail); stores are guarded
        const unsigned short* ap = A + (size_t)row * K + lg * 8;
        #pragma unroll
        for (int ks = 0; ks < KS; ++ks) {
            bf16x8 af = *(const bf16x8*)(ap + ks * 32);
            #pragma unroll
            for (int n = 0; n < 4; ++n)
                acc[m][n] = __builtin_amdgcn_mfma_f32_16x16x32_bf16(af, bfrag[n][ks], acc[m][n], 0, 0, 0);
        }
    }

    // epilogue: es/ed (f32) + stage h (bf16) in LDS
    float asv[4], adv[4];
    #pragma unroll
    for (int n = 0; n < 4; ++n) {
        asv[n] = a_s[head * 64 + n * 16 + l15];
        adv[n] = a_d[head * 64 + n * 16 + l15];
    }
    #pragma unroll
    for (int m = 0; m < 4; ++m) {
        #pragma unroll
        for (int r = 0; r < 4; ++r) {
            int rloc = m * 16 + lg * 4 + r;        // C/D layout: col=lane&15, row=(lane>>4)*4+r
            float ps = 0.f, pd = 0.f;
            #pragma unroll
            for (int n = 0; n < 4; ++n) {
                float v = acc[m][n][r];
                ps += v * asv[n];
                pd += v * adv[n];
                hstage[rloc][head * 64 + n * 16 + l15] = f2bf(v);
            }
            #pragma unroll
            for (int o = 8; o; o >>= 1) { ps += __shfl_xor(ps, o, 64); pd += __shfl_xor(pd, o, 64); }
            int rg = row0 + rloc;
            if (l15 == 0 && rg < M) { es[rg * 4 + head] = ps; ed[rg * 4 + head] = pd; }
        }
    }
    __syncthreads();
    // cooperative coalesced store: 64 rows x 256 cols bf16
    #pragma unroll
    for (int it = 0; it < 8; ++it) {
        int id = threadIdx.x + it * 256;
        int row = id >> 5, c8 = (id & 31) * 8;
        int rg = row0 + row;
        if (rg < M) {
            int4 v = *(const int4*)(&hstage[row][c8]);
            *(int4*)(h_bf + (size_t)rg * HDIM + c8) = v;
        }
    }
}

// ---------------- fused softmax + weighted gather: one wave per dst node ----------------
template<bool LAST>
__global__ __launch_bounds__(256) void gather_kernel(
    const unsigned short* __restrict__ h_bf,
    const float4* __restrict__ es4, const float4* __restrict__ ed4,
    const int* __restrict__ offs, const int* __restrict__ csrc,
    const float* __restrict__ bias,
    const float* __restrict__ fcW, const float* __restrict__ fcb,
    unsigned short* __restrict__ xout_bf, float* __restrict__ out)
{
    __shared__ float wls[4][64][4];   // per-wave: chunk edge weights
    __shared__ int   sls[4][64];      // per-wave: chunk src indices
    const int wv = threadIdx.x >> 6;
    const int lane = threadIdx.x & 63;
    const int w = blockIdx.x * 4 + wv;
    const int hd = lane >> 4;
    const int ch = lane << 2;
    const int beg = offs[w], end = offs[w + 1];
    const float4 edv = ed4[w];

    // sweep 1: per-head max over this node's edges (es is L2-hot, 800 KB)
    float4 mx = {-INFINITY, -INFINITY, -INFINITY, -INFINITY};
    for (int i = beg + lane; i < end; i += 64) {
        float4 e = es4[csrc[i]];
        e.x += edv.x; e.y += edv.y; e.z += edv.z; e.w += edv.w;
        e.x = (e.x > 0.f) ? e.x : NEG_SLOPE * e.x;
        e.y = (e.y > 0.f) ? e.y : NEG_SLOPE * e.y;
        e.z = (e.z > 0.f) ? e.z : NEG_SLOPE * e.z;
        e.w = (e.w > 0.f) ? e.w : NEG_SLOPE * e.w;
        mx.x = fmaxf(mx.x, e.x); mx.y = fmaxf(mx.y, e.y);
        mx.z = fmaxf(mx.z, e.z); mx.w = fmaxf(mx.w, e.w);
    }
    #pragma unroll
    for (int o = 32; o; o >>= 1) {
        mx.x = fmaxf(mx.x, __shfl_xor(mx.x, o, 64));
        mx.y = fmaxf(mx.y, __shfl_xor(mx.y, o, 64));
        mx.z = fmaxf(mx.z, __shfl_xor(mx.z, o, 64));
        mx.w = fmaxf(mx.w, __shfl_xor(mx.w, o, 64));
    }

    // sweep 2: per 64-edge chunk: w=exp(e-mx) -> LDS, then weighted h-gather
    float4 zac = {0.f, 0.f, 0.f, 0.f};
    float4 acc = {0.f, 0.f, 0.f, 0.f};
    for (int c0 = beg; c0 < end; c0 += 64) {
        int i = c0 + lane;
        float4 wt = {0.f, 0.f, 0.f, 0.f};
        int sidx = 0;
        if (i < end) {
            sidx = csrc[i];
            float4 e = es4[sidx];
            e.x += edv.x; e.y += edv.y; e.z += edv.z; e.w += edv.w;
            e.x = (e.x > 0.f) ? e.x : NEG_SLOPE * e.x;
            e.y = (e.y > 0.f) ? e.y : NEG_SLOPE * e.y;
            e.z = (e.z > 0.f) ? e.z : NEG_SLOPE * e.z;
            e.w = (e.w > 0.f) ? e.w : NEG_SLOPE * e.w;
            wt.x = __expf(e.x - mx.x); wt.y = __expf(e.y - mx.y);
            wt.z = __expf(e.z - mx.z); wt.w = __expf(e.w - mx.w);
        }
        sls[wv][lane] = sidx;
        *(float4*)(&wls[wv][lane][0]) = wt;
        zac.x += wt.x; zac.y += wt.y; zac.z += wt.z; zac.w += wt.w;
        int nb = end - c0; if (nb > 64) nb = 64;
        int j = 0;
        for (; j + 3 < nb; j += 4) {
            int s0 = sls[wv][j], s1 = sls[wv][j + 1], s2 = sls[wv][j + 2], s3 = sls[wv][j + 3];
            float a0 = wls[wv][j][hd],     a1 = wls[wv][j + 1][hd];
            float a2 = wls[wv][j + 2][hd], a3 = wls[wv][j + 3][hd];
            ushort4 u0 = *(const ushort4*)(h_bf + (size_t)s0 * HDIM + ch);
            ushort4 u1 = *(const ushort4*)(h_bf + (size_t)s1 * HDIM + ch);
            ushort4 u2 = *(const ushort4*)(h_bf + (size_t)s2 * HDIM + ch);
            ushort4 u3 = *(const ushort4*)(h_bf + (size_t)s3 * HDIM + ch);
            acc.x += a0 * b2f(u0.x) + a1 * b2f(u1.x) + a2 * b2f(u2.x) + a3 * b2f(u3.x);
            acc.y += a0 * b2f(u0.y) + a1 * b2f(u1.y) + a2 * b2f(u2.y) + a3 * b2f(u3.y);
            acc.z += a0 * b2f(u0.z) + a1 * b2f(u1.z) + a2 * b2f(u2.z) + a3 * b2f(u3.z);
            acc.w += a0 * b2f(u0.w) + a1 * b2f(u1.w) + a2 * b2f(u2.w) + a3 * b2f(u3.w);
        }
        for (; j < nb; ++j) {
            int s = sls[wv][j];
            float a = wls[wv][j][hd];
            ushort4 u = *(const ushort4*)(h_bf + (size_t)s * HDIM + ch);
            acc.x += a * b2f(u.x); acc.y += a * b2f(u.y);
            acc.z += a * b2f(u.z); acc.w += a * b2f(u.w);
        }
    }
    // z: full-wave reduction (all lanes end with all 4 head sums)
    #pragma unroll
    for (int o = 32; o; o >>= 1) {
        zac.x += __shfl_xor(zac.x, o, 64);
        zac.y += __shfl_xor(zac.y, o, 64);
        zac.z += __shfl_xor(zac.z, o, 64);
        zac.w += __shfl_xor(zac.w, o, 64);
    }
    float zz = (hd == 0) ? zac.x : (hd == 1) ? zac.y : (hd == 2) ? zac.z : zac.w;
    float inv = 1.f / zz;
    acc.x *= inv; acc.y *= inv; acc.z *= inv; acc.w *= inv;
    // head mean: sum lanes {l, l^16, l^32, l^48}
    acc.x += __shfl_xor(acc.x, 16, 64); acc.x += __shfl_xor(acc.x, 32, 64);
    acc.y += __shfl_xor(acc.y, 16, 64); acc.y += __shfl_xor(acc.y, 32, 64);
    acc.z += __shfl_xor(acc.z, 16, 64); acc.z += __shfl_xor(acc.z, 32, 64);
    acc.w += __shfl_xor(acc.w, 16, 64); acc.w += __shfl_xor(acc.w, 32, 64);
    if (lane < 16) {
        float4 bv = *(const float4*)(bias + ch);
        float4 r;
        r.x = gelu_exact(0.25f * acc.x + bv.x);
        r.y = gelu_exact(0.25f * acc.y + bv.y);
        r.z = gelu_exact(0.25f * acc.z + bv.z);
        r.w = gelu_exact(0.25f * acc.w + bv.w);
        if (!LAST) {
            ushort4 o4;
            o4.x = f2bf(r.x); o4.y = f2bf(r.y); o4.z = f2bf(r.z); o4.w = f2bf(r.w);
            *(ushort4*)(xout_bf + (size_t)w * HID + ch) = o4;
        } else {
            float p = r.x * fcW[ch] + r.y * fcW[ch + 1] + r.z * fcW[ch + 2] + r.w * fcW[ch + 3];
            #pragma unroll
            for (int o = 8; o; o >>= 1) p += __shfl_xor(p, o, 64);
            if (lane == 0) out[w] = 1.f / (1.f + __expf(-(p + fcb[0])));
        }
    }
}

extern "C" void kernel_launch(void* const* d_in, const int* in_sizes, int n_in,
                              void* d_out, int out_size, void* d_ws, size_t ws_size,
                              hipStream_t stream) {
    const float* x    = (const float*)d_in[0];
    const int*   ei   = (const int*)d_in[1];
    const float* W1   = (const float*)d_in[2];
    const float* as1  = (const float*)d_in[3];
    const float* ad1  = (const float*)d_in[4];
    const float* b1   = (const float*)d_in[5];
    const float* W2   = (const float*)d_in[6];
    const float* as2  = (const float*)d_in[7];
    const float* ad2  = (const float*)d_in[8];
    const float* b2   = (const float*)d_in[9];
    const float* W3   = (const float*)d_in[10];
    const float* as3  = (const float*)d_in[11];
    const float* ad3  = (const float*)d_in[12];
    const float* b3   = (const float*)d_in[13];
    const float* fcW  = (const float*)d_in[14];
    const float* fcb  = (const float*)d_in[15];
    float* out = (float*)d_out;

    char* ws = (char*)d_ws;
    size_t off = 0;
    auto alloc = [&](size_t bytes) -> void* {
        void* p = ws + off;
        off += (bytes + 255) & ~(size_t)255;
        return p;
    };
    unsigned short* h_bf  = (unsigned short*)alloc((size_t)N_NODES * HDIM * 2);   // 25.6 MB
    unsigned short* x_bf  = (unsigned short*)alloc((size_t)N_NODES * DIM_IN * 2); // 12.8 MB
    unsigned short* xA_bf = (unsigned short*)alloc((size_t)N_NODES * HID * 2);    // 6.4 MB
    unsigned short* xB_bf = (unsigned short*)alloc((size_t)N_NODES * HID * 2);    // 6.4 MB
    unsigned short* Wt1   = (unsigned short*)alloc((size_t)HDIM * DIM_IN * 2);
    unsigned short* Wt2   = (unsigned short*)alloc((size_t)HDIM * HID * 2);
    unsigned short* Wt3   = (unsigned short*)alloc((size_t)HDIM * HID * 2);
    float* esb   = (float*)alloc((size_t)N_NODES * 4 * 4);
    float* edb   = (float*)alloc((size_t)N_NODES * 4 * 4);
    int* offs    = (int*)alloc((size_t)(N_NODES + 1) * 4);
    int* counts  = (int*)alloc((size_t)2 * N_NODES * 4);
    int* cursor  = counts + N_NODES;
    int* bsums   = (int*)alloc(256 * 4);
    int* bscan   = (int*)alloc(256 * 4);
    int* csrc    = (int*)alloc((size_t)ETOT * 4);                                  // 3.4 MB

    const int NB    = (N_NODES + 255) / 256;       // 196
    const int EB    = (ETOT + 255) / 256;          // 3321
    const int GB    = (N_NODES + 63) / 64;         // 782  (gemm blocks)
    const int AGB   = N_NODES / 4;                 // 12500 (gather blocks, 4 nodes each)
    const int CXB   = (N_NODES * DIM_IN / 4 + 255) / 256;  // 6250

    // CSR build (ws re-poisoned each call -> rebuild)
    hipMemsetAsync(counts, 0, (size_t)2 * N_NODES * 4, stream);
    count_kernel<<<EB, 256, 0, stream>>>(ei, counts);
    scan1_kernel<<<NB, 256, 0, stream>>>(counts, offs, bsums);
    scan2_kernel<<<1, 256, 0, stream>>>(bsums, bscan, NB);
    scan3_kernel<<<NB, 256, 0, stream>>>(offs, bscan);
    fill_kernel<<<EB, 256, 0, stream>>>(ei, offs, cursor, csrc);

    // dtype conversion
    convx_kernel<<<CXB, 256, 0, stream>>>((const float4*)x, (ushort4*)x_bf, N_NODES * DIM_IN / 4);
    convw_kernel<<<256, 256, 0, stream>>>(W1, W2, W3, Wt1, Wt2, Wt3);

    // layer 1
    gemm_mfma_kernel<DIM_IN><<<GB, 256, 0, stream>>>(x_bf, Wt1, as1, ad1, h_bf, esb, edb, N_NODES);
    gather_kernel<false><<<AGB, 256, 0, stream>>>(h_bf, (const float4*)esb, (const float4*)edb,
                                                  offs, csrc, b1, fcW, fcb, xA_bf, out);
    // layer 2
    gemm_mfma_kernel<HID><<<GB, 256, 0, stream>>>(xA_bf, Wt2, as2, ad2, h_bf, esb, edb, N_NODES);
    gather_kernel<false><<<AGB, 256, 0, stream>>>(h_bf, (const float4*)esb, (const float4*)edb,
                                                  offs, csrc, b2, fcW, fcb, xB_bf, out);
    // layer 3 (+ fused final linear + sigmoid)
    gemm_mfma_kernel<HID><<<GB, 256, 0, stream>>>(xB_bf, Wt3, as3, ad3, h_bf, esb, edb, N_NODES);
    gather_kernel<true><<<AGB, 256, 0, stream>>>(h_bf, (const float4*)esb, (const float4*)edb,
                                                 offs, csrc, b3, fcW, fcb, xA_bf, out);
}